// Round 13
// baseline (967.193 us; speedup 1.0000x reference)
//
#include <hip/hip_runtime.h>

#define D 128
#define NG 64
#define NL 3
#define NPART 8

typedef __attribute__((ext_vector_type(8))) short bf16x8;
typedef __attribute__((ext_vector_type(4))) float f32x4;
typedef unsigned short u16;
typedef unsigned int   u32;
typedef unsigned long long u64;

__device__ __forceinline__ u16 f2bf(float x) {   // RNE
  u32 u = __float_as_uint(x);
  return (u16)((u + 0x7FFF + ((u >> 16) & 1)) >> 16);
}
__device__ __forceinline__ float bf2f(u16 b) {
  return __uint_as_float((u32)b << 16);
}

// ================= CSR build, two-phase bucketize =================
// B0: per-partition edge counts (LDS histogram, 8 global atomics/block)
__global__ void k_pcount(const int* __restrict__ dst, int* __restrict__ pcnt,
                         int E, int psize) {
  __shared__ int lc[NPART];
  if (threadIdx.x < NPART) lc[threadIdx.x] = 0;
  __syncthreads();
  int i = blockIdx.x * blockDim.x + threadIdx.x;
  int stride = gridDim.x * blockDim.x;
  for (; i < E; i += stride)
    atomicAdd(&lc[__builtin_nontemporal_load(&dst[i]) / psize], 1);
  __syncthreads();
  if (threadIdx.x < NPART) atomicAdd(&pcnt[threadIdx.x], lc[threadIdx.x]);
}

__global__ void k_scan8(const int* __restrict__ pcnt, int* __restrict__ pbase,
                        int* __restrict__ pfill) {
  if (threadIdx.x == 0) {
    int run = 0;
    for (int p = 0; p < NPART; ++p) { pbase[p] = run; pfill[p] = run; run += pcnt[p]; }
  }
}

// B1: bucketize edges into contiguous per-partition staging (coalesced writes)
__global__ __launch_bounds__(256) void k_bucket(
    const int* __restrict__ src, const int* __restrict__ dst,
    u64* __restrict__ staged, int* __restrict__ pfill, int E, int psize) {
  __shared__ u64 buf[NPART][320];
  __shared__ int bcnt[NPART];
  __shared__ int gbase[NPART];
  const int tid = threadIdx.x;
  if (tid < NPART) bcnt[tid] = 0;
  __syncthreads();

  const int total_chunks = (E + 255) / 256;
  for (int c = blockIdx.x; c < total_chunks; c += gridDim.x) {
    int i = c * 256 + tid;
    if (i < E) {
      int t = __builtin_nontemporal_load(&dst[i]);
      int s = __builtin_nontemporal_load(&src[i]);
      int p = t / psize;
      u64 pk = ((u64)(u32)t << 32) | (u32)s;
      int slot = atomicAdd(&bcnt[p], 1);     // LDS atomic
      buf[p][slot] = pk;
    }
    __syncthreads();
    // flush multiples of 64 (block-uniform control flow)
    for (int q = 0; q < NPART; ++q) {
      int cq = bcnt[q];
      int f  = cq & ~63;
      if (f > 0) {
        if (tid == 0) gbase[q] = atomicAdd(&pfill[q], f);
        __syncthreads();
        int gb = gbase[q];
        for (int j = tid; j < f; j += 256) staged[gb + j] = buf[q][j];
        __syncthreads();
        int rem = cq - f;
        if (tid < rem) buf[q][tid] = buf[q][f + tid];   // rem<64<=f: no overlap
        __syncthreads();
        if (tid == 0) bcnt[q] = rem;
        __syncthreads();
      }
    }
    __syncthreads();
  }
  // final flush
  for (int q = 0; q < NPART; ++q) {
    int cq = bcnt[q];
    if (cq > 0) {
      if (tid == 0) gbase[q] = atomicAdd(&pfill[q], cq);
      __syncthreads();
      int gb = gbase[q];
      for (int j = tid; j < cq; j += 256) staged[gb + j] = buf[q][j];
    }
    __syncthreads();
  }
}

// C1: per-partition degree count (L2-local atomics)
__global__ void k_lcount(const u64* __restrict__ staged,
                         const int* __restrict__ pbase, const int* __restrict__ pcnt,
                         int* __restrict__ cnt) {
  int p  = blockIdx.x & (NPART - 1);
  int nb = gridDim.x >> 3;
  int bi = blockIdx.x >> 3;
  int lo = pbase[p], ce = pcnt[p];
  for (int j = bi * blockDim.x + threadIdx.x; j < ce; j += nb * blockDim.x) {
    u64 pk = staged[lo + j];
    atomicAdd(&cnt[(int)(pk >> 32)], 1);
  }
}

// C2: per-partition fill (L2-local scatter)
__global__ void k_lfill(const u64* __restrict__ staged,
                        const int* __restrict__ pbase, const int* __restrict__ pcnt,
                        int* __restrict__ cursor, int* __restrict__ csr_src) {
  int p  = blockIdx.x & (NPART - 1);
  int nb = gridDim.x >> 3;
  int bi = blockIdx.x >> 3;
  int lo = pbase[p], ce = pcnt[p];
  for (int j = bi * blockDim.x + threadIdx.x; j < ce; j += nb * blockDim.x) {
    u64 pk = staged[lo + j];
    int t = (int)(pk >> 32);
    int pos = atomicAdd(&cursor[t], 1);
    csr_src[pos] = (int)(u32)pk;
  }
}

__global__ void k_invdeg(const int* __restrict__ cnt, float* __restrict__ invdeg, int n) {
  int i = blockIdx.x * blockDim.x + threadIdx.x;
  if (i < n) invdeg[i] = 1.0f / (float)max(cnt[i], 1);
}

__global__ void k_blocksum(const int* __restrict__ cnt, int* __restrict__ bsum, int n) {
  int b = blockIdx.x, t = threadIdx.x;
  int base = b * 1024 + t * 4;
  int s = 0;
#pragma unroll
  for (int j = 0; j < 4; ++j) if (base + j < n) s += cnt[base + j];
  int lane = t & 63, w = t >> 6;
#pragma unroll
  for (int m = 1; m < 64; m <<= 1) s += __shfl_xor(s, m);
  __shared__ int ws[4];
  if (lane == 0) ws[w] = s;
  __syncthreads();
  if (t == 0) bsum[b] = ws[0] + ws[1] + ws[2] + ws[3];
}

__global__ void k_scan_bsum(int* __restrict__ bsum, int nb) {
  __shared__ int s[1024];
  int t = threadIdx.x;
  int v = t < nb ? bsum[t] : 0;
  s[t] = v;
  __syncthreads();
  for (int off = 1; off < 1024; off <<= 1) {
    int x = (t >= off) ? s[t - off] : 0;
    __syncthreads();
    s[t] += x;
    __syncthreads();
  }
  if (t < nb) bsum[t] = s[t] - v;   // exclusive
}

__global__ void k_rowptr(const int* __restrict__ cnt, const int* __restrict__ bsum,
                         int* __restrict__ rowptr, int* __restrict__ cursor, int n) {
  int b = blockIdx.x, t = threadIdx.x;
  int base = b * 1024 + t * 4;
  int v0 = 0, v1 = 0, v2 = 0, v3 = 0;
  if (base + 0 < n) v0 = cnt[base + 0];
  if (base + 1 < n) v1 = cnt[base + 1];
  if (base + 2 < n) v2 = cnt[base + 2];
  if (base + 3 < n) v3 = cnt[base + 3];
  int ts = v0 + v1 + v2 + v3;
  int lane = t & 63, w = t >> 6;
  int incl = ts;
#pragma unroll
  for (int m = 1; m < 64; m <<= 1) {
    int o = __shfl_up(incl, m);
    if (lane >= m) incl += o;
  }
  __shared__ int wsum[4];
  if (lane == 63) wsum[w] = incl;
  __syncthreads();
  int woff = 0;
  for (int i = 0; i < w; ++i) woff += wsum[i];
  int run = incl - ts + woff + bsum[b];
  if (base + 0 < n) { rowptr[base + 0] = run; cursor[base + 0] = run; run += v0; }
  if (base + 1 < n) { rowptr[base + 1] = run; cursor[base + 1] = run; run += v1; }
  if (base + 2 < n) { rowptr[base + 2] = run; cursor[base + 2] = run; run += v2; }
  if (base + 3 < n) { rowptr[base + 3] = run; cursor[base + 3] = run; run += v3; }
}

// ================= weight prep: Wt[m][n][k] = bf16(W[m][k][n]) =================
__global__ void k_wprep(const float* __restrict__ W, u16* __restrict__ Wt, int nmats) {
  long idx = (long)blockIdx.x * blockDim.x + threadIdx.x;
  long total = (long)nmats * 16384;
  long stride = (long)gridDim.x * blockDim.x;
  for (; idx < total; idx += stride) {
    long m = idx >> 14;
    int o = (int)(idx & 16383);
    int nn = o >> 7, k = o & 127;
    Wt[idx] = f2bf(W[m * 16384 + k * 128 + nn]);
  }
}

// ================= aggregation: aggB[i] = bf16(mean_{e: dst=i} node[src[e]]) =========
__global__ void k_aggr(const u16* __restrict__ nodeB,
                       const int* __restrict__ rowptr, const int* __restrict__ rowend,
                       const float* __restrict__ invdeg,
                       const int* __restrict__ csr_src,
                       u16* __restrict__ aggB, int n) {
  const int tid  = threadIdx.x;
  const int lane = tid & 63;
  const int l15  = lane & 15;
  const int g    = lane >> 4;                               // group 0..3
  const int wav  = (blockIdx.x * blockDim.x + tid) >> 6;
  const int node = wav * 4 + g;
  if (node >= n) return;

  const int s0 = rowptr[node];
  const int nk = rowend[node] - s0;
  const long off = (long)l15 * 8;                           // 8 bf16 per lane

  float acc[8] = {};

  for (int kb = 0; kb < nk; kb += 16) {
    const int rem = min(16, nk - kb);
    int myidx = (l15 < rem) ? csr_src[s0 + kb + l15] : 0;   // 64B coalesced per group
    int kk = 0;
    for (; kk + 8 <= rem; kk += 8) {
      bf16x8 v[8];
#pragma unroll
      for (int j = 0; j < 8; ++j) {
        int s = __shfl(myidx, (g << 4) + kk + j);           // in-register broadcast
        v[j] = *(const bf16x8*)&nodeB[(long)s * D + off];   // 8 independent gathers
      }
#pragma unroll
      for (int j = 0; j < 8; ++j)
#pragma unroll
        for (int e = 0; e < 8; ++e)
          acc[e] += bf2f((u16)v[j][e]);
    }
    for (; kk + 4 <= rem; kk += 4) {
      bf16x8 v[4];
#pragma unroll
      for (int j = 0; j < 4; ++j) {
        int s = __shfl(myidx, (g << 4) + kk + j);
        v[j] = *(const bf16x8*)&nodeB[(long)s * D + off];
      }
#pragma unroll
      for (int j = 0; j < 4; ++j)
#pragma unroll
        for (int e = 0; e < 8; ++e)
          acc[e] += bf2f((u16)v[j][e]);
    }
    for (; kk < rem; ++kk) {
      int s = __shfl(myidx, (g << 4) + kk);
      bf16x8 v = *(const bf16x8*)&nodeB[(long)s * D + off];
#pragma unroll
      for (int e = 0; e < 8; ++e) acc[e] += bf2f((u16)v[e]);
    }
  }

  const float sc = invdeg[node];
  bf16x8 ov;
#pragma unroll
  for (int e = 0; e < 8; ++e) ov[e] = (short)f2bf(acc[e] * sc);
  *(bf16x8*)&aggB[(long)node * D + off] = ov;               // 16B coalesced store
}

// ================= MFMA projection: nodeB = bf16(X @ W + b) =================
__global__ __launch_bounds__(256) void k_proj_mfma(
    const float* __restrict__ X, const u16* __restrict__ WT,   // [n][k] bf16
    const float* __restrict__ bias, u16* __restrict__ OutB, int n)
{
  const int tid  = threadIdx.x;
  const int lane = tid & 63;
  const int w    = tid >> 6;
  const int l15  = lane & 15;
  const int g    = lane >> 4;
  const long base = (long)blockIdx.x * 64;

  long arow  = base + w * 16 + l15;
  long arowc = arow < n ? arow : (n - 1);

  bf16x8 aX[4];
#pragma unroll
  for (int ks = 0; ks < 4; ++ks) {
    int k0 = ks * 32 + g * 8;
    float4 x0 = *(const float4*)&X[arowc * D + k0];
    float4 x1 = *(const float4*)&X[arowc * D + k0 + 4];
    bf16x8 a;
    a[0] = (short)f2bf(x0.x); a[1] = (short)f2bf(x0.y);
    a[2] = (short)f2bf(x0.z); a[3] = (short)f2bf(x0.w);
    a[4] = (short)f2bf(x1.x); a[5] = (short)f2bf(x1.y);
    a[6] = (short)f2bf(x1.z); a[7] = (short)f2bf(x1.w);
    aX[ks] = a;
  }

  f32x4 acc[8] = {};
#pragma unroll
  for (int f = 0; f < 8; ++f) {
    int nn = f * 16 + l15;
#pragma unroll
    for (int ks = 0; ks < 4; ++ks) {
      int k0 = ks * 32 + g * 8;
      bf16x8 bW = *(const bf16x8*)&WT[nn * D + k0];
      acc[f] = __builtin_amdgcn_mfma_f32_16x16x32_bf16(aX[ks], bW, acc[f], 0, 0, 0);
    }
  }

  float bs[8];
#pragma unroll
  for (int f = 0; f < 8; ++f) bs[f] = bias[f * 16 + l15];

#pragma unroll
  for (int r = 0; r < 4; ++r) {
    long row = base + w * 16 + g * 4 + r;
    if (row >= n) continue;
#pragma unroll
    for (int f = 0; f < 8; ++f)
      OutB[row * D + f * 16 + l15] = f2bf(acc[f][r] + bs[f]);
  }
}

// ================= MFMA conv: h = node@Ws + agg@Wn + b =================
// 512 threads = 8 waves x 16 rows. Weights staged once per block into LDS
// with XOR swizzle (col8 ^= row&15) -> conflict-light ds_read_b128.
// fused: gacc += segsum(h) ; node' = relu(LN(h + node))
__global__ __launch_bounds__(512, 4) void k_conv_mfma(
    const u16* __restrict__ nodeB, const u16* __restrict__ aggB,
    const u16* __restrict__ WsT, const u16* __restrict__ WnT,   // [n][k] bf16
    const float* __restrict__ bias,
    const float* __restrict__ lg, const float* __restrict__ lb,
    const int* __restrict__ batch,
    float* __restrict__ gacc,
    u16* __restrict__ nodeOutB, float* __restrict__ nodeOutF,
    int n)
{
  __shared__ u16 w_lds[2 * D * D];    // 64 KB: rows 0-127 = Ws, 128-255 = Wn
  __shared__ int batch_lds[128];
  const int tid  = threadIdx.x;
  const int lane = tid & 63;
  const int w    = tid >> 6;        // wave 0..7, owns rows w*16..w*16+15
  const int l15  = lane & 15;
  const int g    = lane >> 4;       // 0..3
  const long base = (long)blockIdx.x * 128;

  if (tid < 128) {
    long r = base + tid;
    batch_lds[tid] = batch[r < n ? r : (n - 1)];
  }

  // ---- A fragments first (global latency hides under weight staging) ----
  long arow  = base + w * 16 + l15;
  long arowc = arow < n ? arow : (n - 1);
  bf16x8 aS[4], aA[4];
#pragma unroll
  for (int ks = 0; ks < 4; ++ks) {
    int k0 = ks * 32 + g * 8;
    aS[ks] = *(const bf16x8*)&nodeB[arowc * D + k0];
    aA[ks] = *(const bf16x8*)&aggB [arowc * D + k0];
  }

  // ---- stage weights: 4096 x 16B chunks, swizzled ----
#pragma unroll
  for (int it = 0; it < 8; ++it) {
    int c    = it * 512 + tid;       // chunk id (16B each)
    int row  = c >> 4;               // 0..255
    int col8 = c & 15;               // 16B slot within row
    const u16* src = (c < 2048) ? &WsT[(long)c * 8] : &WnT[(long)(c - 2048) * 8];
    bf16x8 v = *(const bf16x8*)src;
    *(bf16x8*)&w_lds[row * D + (((col8) ^ (row & 15)) << 3)] = v;
  }
  __syncthreads();

  // ---- MFMA loop, weights from LDS (swizzled read) ----
  f32x4 acc[8] = {};
#pragma unroll
  for (int f = 0; f < 8; ++f) {
    const int wrow = f * 16 + l15;
#pragma unroll
    for (int ks = 0; ks < 4; ++ks) {
      const int cs = ((ks * 4 + g) ^ l15) << 3;   // row&15 == l15
      bf16x8 bS = *(const bf16x8*)&w_lds[wrow * D + cs];
      bf16x8 bA = *(const bf16x8*)&w_lds[D * D + wrow * D + cs];
      acc[f] = __builtin_amdgcn_mfma_f32_16x16x32_bf16(aS[ks], bS, acc[f], 0, 0, 0);
      acc[f] = __builtin_amdgcn_mfma_f32_16x16x32_bf16(aA[ks], bA, acc[f], 0, 0, 0);
    }
  }

  // ---- epilogue params (col = f*16 + l15) ----
  float bs[8], lgv[8], lbv[8];
#pragma unroll
  for (int f = 0; f < 8; ++f) {
    bs[f]  = bias[f * 16 + l15];
    lgv[f] = lg[f * 16 + l15];
    lbv[f] = lb[f * 16 + l15];
  }
#pragma unroll
  for (int f = 0; f < 8; ++f)
#pragma unroll
    for (int r = 0; r < 4; ++r) acc[f][r] += bs[f];

  long rowb[4];
  bool valid[4];
#pragma unroll
  for (int r = 0; r < 4; ++r) {
    rowb[r]  = base + w * 16 + g * 4 + r;
    valid[r] = rowb[r] < n;
  }

  // ---- graph segment sum over this wave's 16 rows (batch sorted) ----
  const int wb = w * 16;
  int b_first = batch_lds[wb], b_last = batch_lds[wb + 15];
  if (b_first == b_last) {
#pragma unroll
    for (int f = 0; f < 8; ++f) {
      float ps = 0.f;
#pragma unroll
      for (int r = 0; r < 4; ++r) if (valid[r]) ps += acc[f][r];
      ps += __shfl_xor(ps, 16);
      ps += __shfl_xor(ps, 32);
      if (lane < 16) atomicAdd(&gacc[b_first * D + f * 16 + lane], ps);
    }
  } else {
    int i = 0;
    while (i < 16) {                    // wave-uniform (LDS scalars)
      int bseg = batch_lds[wb + i];
      int j = i + 1;
      while (j < 16 && batch_lds[wb + j] == bseg) ++j;
#pragma unroll
      for (int f = 0; f < 8; ++f) {
        float ps = 0.f;
#pragma unroll
        for (int r = 0; r < 4; ++r) {
          int lr = g * 4 + r;
          if (valid[r] && lr >= i && lr < j) ps += acc[f][r];
        }
        ps += __shfl_xor(ps, 16);
        ps += __shfl_xor(ps, 32);
        if (lane < 16) atomicAdd(&gacc[bseg * D + f * 16 + lane], ps);
      }
      i = j;
    }
  }

  // ---- residual + LN + relu ----
  float xv[8][4];
  float s[4] = {0, 0, 0, 0}, q[4] = {0, 0, 0, 0};
#pragma unroll
  for (int r = 0; r < 4; ++r) {
    long row = valid[r] ? rowb[r] : (n - 1);
#pragma unroll
    for (int f = 0; f < 8; ++f) {
      float nv = bf2f(nodeB[row * D + f * 16 + l15]);
      float x  = acc[f][r] + nv;
      xv[f][r] = x;
      s[r] += x; q[r] += x * x;
    }
  }
#pragma unroll
  for (int r = 0; r < 4; ++r) {
#pragma unroll
    for (int m = 1; m < 16; m <<= 1) {
      s[r] += __shfl_xor(s[r], m);
      q[r] += __shfl_xor(q[r], m);
    }
  }
#pragma unroll
  for (int r = 0; r < 4; ++r) {
    if (!valid[r]) continue;
    float mean = s[r] * (1.f / 128.f);
    float var  = q[r] * (1.f / 128.f) - mean * mean;
    float rs   = rsqrtf(fmaxf(var, 0.f) + 1e-5f);
#pragma unroll
    for (int f = 0; f < 8; ++f) {
      float y = fmaxf((xv[f][r] - mean) * rs * lgv[f] + lbv[f], 0.f);
      if (nodeOutB) nodeOutB[rowb[r] * D + f * 16 + l15] = f2bf(y);
      if (nodeOutF) nodeOutF[rowb[r] * D + f * 16 + l15] = y;
    }
  }
}

// ================= graph LN: graph = LN(LN(gacc + graph)) =================
__global__ void k_ln_graph(const float* __restrict__ gacc,
                           float* __restrict__ graph,
                           const float* __restrict__ lg,
                           const float* __restrict__ lb)
{
  int row  = blockIdx.x;
  int lane = threadIdx.x;
  float2 gv = *(const float2*)&lg[lane * 2];
  float2 bv = *(const float2*)&lb[lane * 2];
  float2 a = *(const float2*)&gacc[row * D + lane * 2];
  float2 p = *(const float2*)&graph[row * D + lane * 2];
  float x0 = a.x + p.x, x1 = a.y + p.y;
#pragma unroll
  for (int pass = 0; pass < 2; ++pass) {
    float s = x0 + x1, q = x0 * x0 + x1 * x1;
#pragma unroll
    for (int m = 1; m < 64; m <<= 1) { s += __shfl_xor(s, m); q += __shfl_xor(q, m); }
    float mean = s * (1.f / 128.f);
    float var  = q * (1.f / 128.f) - mean * mean;
    float rs   = rsqrtf(fmaxf(var, 0.f) + 1e-5f);
    x0 = (x0 - mean) * rs * gv.x + bv.x;
    x1 = (x1 - mean) * rs * gv.y + bv.y;
  }
  float2 o; o.x = x0; o.y = x1;
  *(float2*)&graph[row * D + lane * 2] = o;
}

extern "C" void kernel_launch(void* const* d_in, const int* in_sizes, int n_in,
                              void* d_out, int out_size, void* d_ws, size_t ws_size,
                              hipStream_t stream)
{
  const float* x       = (const float*)d_in[0];
  const int*   edge    = (const int*)d_in[1];
  const int*   batch   = (const int*)d_in[2];
  const float* fc_w    = (const float*)d_in[3];
  const float* fc_b    = (const float*)d_in[4];
  const float* w_self  = (const float*)d_in[5];
  const float* w_neigh = (const float*)d_in[6];
  const float* conv_b  = (const float*)d_in[7];
  const float* ln_g    = (const float*)d_in[8];
  const float* ln_b    = (const float*)d_in[9];

  const int N = in_sizes[0] / D;
  const int E = in_sizes[1] / 2;
  const int* src = edge;
  const int* dst = edge + E;

  // ---- workspace layout ----
  int*   cnt      = (int*)d_ws;                 // N
  int*   rowptr   = cnt + N;                    // N
  int*   cursor   = rowptr + N;                 // N (ends as row-end)
  int*   bsum     = cursor + N;                 // 1024
  int*   pcnt     = bsum + 1024;                // 8
  int*   pbase    = pcnt + NPART;               // 8
  int*   pfill    = pbase + NPART;              // 8
  int*   csr_src  = pfill + NPART;              // E
  float* invdeg   = (float*)(csr_src + E);      // N
  float* gacc     = invdeg + N;                 // G*D
  float* graphbuf = gacc + NG * D;              // G*D
  // 16B-align the bf16 region
  char*  bfbase   = (char*)(graphbuf + NG * D);
  bfbase = (char*)(((size_t)bfbase + 15) & ~(size_t)15);
  u16*   nodeB    = (u16*)bfbase;               // N*D bf16
  u16*   aggB     = nodeB + (long)N * D;        // N*D bf16
  u16*   wsT      = aggB + (long)N * D;         // 3*128*128 bf16
  u16*   wnT      = wsT + 3 * D * D;            // 3*128*128 bf16
  u16*   fcT      = wnT + 3 * D * D;            // 128*128 bf16
  // 8B-align staged u64 region
  char*  stb      = (char*)(fcT + D * D);
  stb = (char*)(((size_t)stb + 7) & ~(size_t)7);
  u64*   staged   = (u64*)stb;                  // E u64

  const int nb = (N + 1023) / 1024;
  const int psize = (N + NPART - 1) / NPART;

  hipMemsetAsync(cnt, 0, (size_t)N * sizeof(int), stream);
  hipMemsetAsync(pcnt, 0, NPART * sizeof(int), stream);
  hipMemsetAsync(graphbuf, 0, (size_t)NG * D * sizeof(float), stream);

  // ---- CSR build: two-phase bucketize ----
  k_pcount<<<2048, 256, 0, stream>>>(dst, pcnt, E, psize);
  k_scan8<<<1, 64, 0, stream>>>(pcnt, pbase, pfill);
  k_bucket<<<2048, 256, 0, stream>>>(src, dst, staged, pfill, E, psize);
  k_lcount<<<2048, 256, 0, stream>>>(staged, pbase, pcnt, cnt);
  k_invdeg<<<(N + 255) / 256, 256, 0, stream>>>(cnt, invdeg, N);
  k_blocksum<<<nb, 256, 0, stream>>>(cnt, bsum, N);
  k_scan_bsum<<<1, 1024, 0, stream>>>(bsum, nb);
  k_rowptr<<<nb, 256, 0, stream>>>(cnt, bsum, rowptr, cursor, N);
  k_lfill<<<2048, 256, 0, stream>>>(staged, pbase, pcnt, cursor, csr_src);

  // ---- weight prep (bf16, transposed to [n][k]) ----
  k_wprep<<<192, 256, 0, stream>>>(w_self,  wsT, NL);
  k_wprep<<<192, 256, 0, stream>>>(w_neigh, wnT, NL);
  k_wprep<<<64, 256, 0, stream>>>(fc_w, fcT, 1);

  // ---- input projection: nodeB = bf16(x @ fc_w + fc_b), MFMA ----
  const int pblocks = (N + 63) / 64;
  k_proj_mfma<<<pblocks, 256, 0, stream>>>(x, fcT, fc_b, nodeB, N);

  const int cblocks = (N + 127) / 128;
  const int ablocks = (N + 15) / 16;
  for (int l = 0; l < NL; ++l) {
    hipMemsetAsync(gacc, 0, (size_t)NG * D * sizeof(float), stream);
    k_aggr<<<ablocks, 256, 0, stream>>>(nodeB, rowptr, cursor, invdeg,
                                        csr_src, aggB, N);
    const bool last = (l == NL - 1);
    k_conv_mfma<<<cblocks, 512, 0, stream>>>(
        nodeB, aggB, wsT + (long)l * D * D, wnT + (long)l * D * D,
        conv_b + l * D, ln_g + l * D, ln_b + l * D,
        batch, gacc,
        last ? nullptr : nodeB, last ? (float*)d_out : nullptr, N);
    k_ln_graph<<<NG, 64, 0, stream>>>(gacc, graphbuf, ln_g + l * D, ln_b + l * D);
  }

  // ---- graph output ----
  hipMemcpyAsync((float*)d_out + (long)N * D, graphbuf,
                 (size_t)NG * D * sizeof(float),
                 hipMemcpyDeviceToDevice, stream);
}

// Round 14
// 478.172 us; speedup vs baseline: 2.0227x; 2.0227x over previous
//
#include <hip/hip_runtime.h>

#define D 128
#define NG 64
#define NL 3
#define NPART 8

typedef __attribute__((ext_vector_type(8))) short bf16x8;
typedef __attribute__((ext_vector_type(4))) float f32x4;
typedef unsigned short u16;
typedef unsigned int   u32;

__device__ __forceinline__ u16 f2bf(float x) {   // RNE
  u32 u = __float_as_uint(x);
  return (u16)((u + 0x7FFF + ((u >> 16) & 1)) >> 16);
}
__device__ __forceinline__ float bf2f(u16 b) {
  return __uint_as_float((u32)b << 16);
}

// ================= CSR build (XCD-partitioned by dst range) =================
__global__ void k_count(const int* __restrict__ dst, int* __restrict__ cnt,
                        int E, int psize) {
  const int myp = blockIdx.x & (NPART - 1);
  const int lo  = myp * psize, hi = lo + psize;
  const int tpp = (gridDim.x / NPART) * blockDim.x;        // threads per partition
  int i = (blockIdx.x >> 3) * blockDim.x + threadIdx.x;
  for (; i < E; i += tpp) {
    int t = dst[i];
    if (t >= lo && t < hi) atomicAdd(&cnt[t], 1);
  }
}

__global__ void k_fill(const int* __restrict__ src, const int* __restrict__ dst,
                       int* __restrict__ cursor, int* __restrict__ csr_src,
                       int E, int psize) {
  const int myp = blockIdx.x & (NPART - 1);
  const int lo  = myp * psize, hi = lo + psize;
  const int tpp = (gridDim.x / NPART) * blockDim.x;
  int i = (blockIdx.x >> 3) * blockDim.x + threadIdx.x;
  for (; i < E; i += tpp) {
    int t = dst[i];
    int s = src[i];                                        // coalesced, L3-served
    if (t >= lo && t < hi) {
      int pos = atomicAdd(&cursor[t], 1);
      csr_src[pos] = s;
    }
  }
}

__global__ void k_invdeg(const int* __restrict__ cnt, float* __restrict__ invdeg, int n) {
  int i = blockIdx.x * blockDim.x + threadIdx.x;
  if (i < n) invdeg[i] = 1.0f / (float)max(cnt[i], 1);
}

__global__ void k_blocksum(const int* __restrict__ cnt, int* __restrict__ bsum, int n) {
  int b = blockIdx.x, t = threadIdx.x;
  int base = b * 1024 + t * 4;
  int s = 0;
#pragma unroll
  for (int j = 0; j < 4; ++j) if (base + j < n) s += cnt[base + j];
  int lane = t & 63, w = t >> 6;
#pragma unroll
  for (int m = 1; m < 64; m <<= 1) s += __shfl_xor(s, m);
  __shared__ int ws[4];
  if (lane == 0) ws[w] = s;
  __syncthreads();
  if (t == 0) bsum[b] = ws[0] + ws[1] + ws[2] + ws[3];
}

__global__ void k_scan_bsum(int* __restrict__ bsum, int nb) {
  __shared__ int s[1024];
  int t = threadIdx.x;
  int v = t < nb ? bsum[t] : 0;
  s[t] = v;
  __syncthreads();
  for (int off = 1; off < 1024; off <<= 1) {
    int x = (t >= off) ? s[t - off] : 0;
    __syncthreads();
    s[t] += x;
    __syncthreads();
  }
  if (t < nb) bsum[t] = s[t] - v;   // exclusive
}

__global__ void k_rowptr(const int* __restrict__ cnt, const int* __restrict__ bsum,
                         int* __restrict__ rowptr, int* __restrict__ cursor, int n) {
  int b = blockIdx.x, t = threadIdx.x;
  int base = b * 1024 + t * 4;
  int v0 = 0, v1 = 0, v2 = 0, v3 = 0;
  if (base + 0 < n) v0 = cnt[base + 0];
  if (base + 1 < n) v1 = cnt[base + 1];
  if (base + 2 < n) v2 = cnt[base + 2];
  if (base + 3 < n) v3 = cnt[base + 3];
  int ts = v0 + v1 + v2 + v3;
  int lane = t & 63, w = t >> 6;
  int incl = ts;
#pragma unroll
  for (int m = 1; m < 64; m <<= 1) {
    int o = __shfl_up(incl, m);
    if (lane >= m) incl += o;
  }
  __shared__ int wsum[4];
  if (lane == 63) wsum[w] = incl;
  __syncthreads();
  int woff = 0;
  for (int i = 0; i < w; ++i) woff += wsum[i];
  int run = incl - ts + woff + bsum[b];
  if (base + 0 < n) { rowptr[base + 0] = run; cursor[base + 0] = run; run += v0; }
  if (base + 1 < n) { rowptr[base + 1] = run; cursor[base + 1] = run; run += v1; }
  if (base + 2 < n) { rowptr[base + 2] = run; cursor[base + 2] = run; run += v2; }
  if (base + 3 < n) { rowptr[base + 3] = run; cursor[base + 3] = run; run += v3; }
}

// ================= weight prep: Wt[m][n][k] = bf16(W[m][k][n]) =================
__global__ void k_wprep(const float* __restrict__ W, u16* __restrict__ Wt, int nmats) {
  long idx = (long)blockIdx.x * blockDim.x + threadIdx.x;
  long total = (long)nmats * 16384;
  long stride = (long)gridDim.x * blockDim.x;
  for (; idx < total; idx += stride) {
    long m = idx >> 14;
    int o = (int)(idx & 16383);
    int nn = o >> 7, k = o & 127;
    Wt[idx] = f2bf(W[m * 16384 + k * 128 + nn]);
  }
}

// ================= aggregation: aggB[i] = bf16(mean_{e: dst=i} node[src[e]]) =========
__global__ void k_aggr(const u16* __restrict__ nodeB,
                       const int* __restrict__ rowptr, const int* __restrict__ rowend,
                       const float* __restrict__ invdeg,
                       const int* __restrict__ csr_src,
                       u16* __restrict__ aggB, int n) {
  const int tid  = threadIdx.x;
  const int lane = tid & 63;
  const int l15  = lane & 15;
  const int g    = lane >> 4;                               // group 0..3
  const int wav  = (blockIdx.x * blockDim.x + tid) >> 6;
  const int node = wav * 4 + g;
  if (node >= n) return;

  const int s0 = rowptr[node];
  const int nk = rowend[node] - s0;
  const long off = (long)l15 * 8;                           // 8 bf16 per lane

  float acc[8] = {};

  for (int kb = 0; kb < nk; kb += 16) {
    const int rem = min(16, nk - kb);
    int myidx = (l15 < rem) ? csr_src[s0 + kb + l15] : 0;   // 64B coalesced per group
    int kk = 0;
    for (; kk + 8 <= rem; kk += 8) {
      bf16x8 v[8];
#pragma unroll
      for (int j = 0; j < 8; ++j) {
        int s = __shfl(myidx, (g << 4) + kk + j);           // in-register broadcast
        v[j] = *(const bf16x8*)&nodeB[(long)s * D + off];   // 8 independent gathers
      }
#pragma unroll
      for (int j = 0; j < 8; ++j)
#pragma unroll
        for (int e = 0; e < 8; ++e)
          acc[e] += bf2f((u16)v[j][e]);
    }
    for (; kk + 4 <= rem; kk += 4) {
      bf16x8 v[4];
#pragma unroll
      for (int j = 0; j < 4; ++j) {
        int s = __shfl(myidx, (g << 4) + kk + j);
        v[j] = *(const bf16x8*)&nodeB[(long)s * D + off];
      }
#pragma unroll
      for (int j = 0; j < 4; ++j)
#pragma unroll
        for (int e = 0; e < 8; ++e)
          acc[e] += bf2f((u16)v[j][e]);
    }
    for (; kk < rem; ++kk) {
      int s = __shfl(myidx, (g << 4) + kk);
      bf16x8 v = *(const bf16x8*)&nodeB[(long)s * D + off];
#pragma unroll
      for (int e = 0; e < 8; ++e) acc[e] += bf2f((u16)v[e]);
    }
  }

  const float sc = invdeg[node];
  bf16x8 ov;
#pragma unroll
  for (int e = 0; e < 8; ++e) ov[e] = (short)f2bf(acc[e] * sc);
  *(bf16x8*)&aggB[(long)node * D + off] = ov;               // 16B coalesced store
}

// ================= MFMA projection: nodeB = bf16(X @ W + b) =================
__global__ __launch_bounds__(256) void k_proj_mfma(
    const float* __restrict__ X, const u16* __restrict__ WT,   // [n][k] bf16
    const float* __restrict__ bias, u16* __restrict__ OutB, int n)
{
  const int tid  = threadIdx.x;
  const int lane = tid & 63;
  const int w    = tid >> 6;
  const int l15  = lane & 15;
  const int g    = lane >> 4;
  const long base = (long)blockIdx.x * 64;

  long arow  = base + w * 16 + l15;
  long arowc = arow < n ? arow : (n - 1);

  bf16x8 aX[4];
#pragma unroll
  for (int ks = 0; ks < 4; ++ks) {
    int k0 = ks * 32 + g * 8;
    float4 x0 = *(const float4*)&X[arowc * D + k0];
    float4 x1 = *(const float4*)&X[arowc * D + k0 + 4];
    bf16x8 a;
    a[0] = (short)f2bf(x0.x); a[1] = (short)f2bf(x0.y);
    a[2] = (short)f2bf(x0.z); a[3] = (short)f2bf(x0.w);
    a[4] = (short)f2bf(x1.x); a[5] = (short)f2bf(x1.y);
    a[6] = (short)f2bf(x1.z); a[7] = (short)f2bf(x1.w);
    aX[ks] = a;
  }

  f32x4 acc[8] = {};
#pragma unroll
  for (int f = 0; f < 8; ++f) {
    int nn = f * 16 + l15;
#pragma unroll
    for (int ks = 0; ks < 4; ++ks) {
      int k0 = ks * 32 + g * 8;
      bf16x8 bW = *(const bf16x8*)&WT[nn * D + k0];
      acc[f] = __builtin_amdgcn_mfma_f32_16x16x32_bf16(aX[ks], bW, acc[f], 0, 0, 0);
    }
  }

  float bs[8];
#pragma unroll
  for (int f = 0; f < 8; ++f) bs[f] = bias[f * 16 + l15];

#pragma unroll
  for (int r = 0; r < 4; ++r) {
    long row = base + w * 16 + g * 4 + r;
    if (row >= n) continue;
#pragma unroll
    for (int f = 0; f < 8; ++f)
      OutB[row * D + f * 16 + l15] = f2bf(acc[f][r] + bs[f]);
  }
}

// ================= MFMA conv: h = node@Ws + agg@Wn + b =================
// 512 threads = 8 waves x 16 rows. Weights staged once per block into LDS
// with XOR swizzle (col8 ^= row&15) -> conflict-light ds_read_b128.
// fused: gacc += segsum(h) ; node' = relu(LN(h + node))
__global__ __launch_bounds__(512, 4) void k_conv_mfma(
    const u16* __restrict__ nodeB, const u16* __restrict__ aggB,
    const u16* __restrict__ WsT, const u16* __restrict__ WnT,   // [n][k] bf16
    const float* __restrict__ bias,
    const float* __restrict__ lg, const float* __restrict__ lb,
    const int* __restrict__ batch,
    float* __restrict__ gacc,
    u16* __restrict__ nodeOutB, float* __restrict__ nodeOutF,
    int n)
{
  __shared__ u16 w_lds[2 * D * D];    // 64 KB: rows 0-127 = Ws, 128-255 = Wn
  __shared__ int batch_lds[128];
  const int tid  = threadIdx.x;
  const int lane = tid & 63;
  const int w    = tid >> 6;        // wave 0..7, owns rows w*16..w*16+15
  const int l15  = lane & 15;
  const int g    = lane >> 4;       // 0..3
  const long base = (long)blockIdx.x * 128;

  if (tid < 128) {
    long r = base + tid;
    batch_lds[tid] = batch[r < n ? r : (n - 1)];
  }

  // ---- A fragments first (global latency hides under weight staging) ----
  long arow  = base + w * 16 + l15;
  long arowc = arow < n ? arow : (n - 1);
  bf16x8 aS[4], aA[4];
#pragma unroll
  for (int ks = 0; ks < 4; ++ks) {
    int k0 = ks * 32 + g * 8;
    aS[ks] = *(const bf16x8*)&nodeB[arowc * D + k0];
    aA[ks] = *(const bf16x8*)&aggB [arowc * D + k0];
  }

  // ---- stage weights: 4096 x 16B chunks, swizzled ----
#pragma unroll
  for (int it = 0; it < 8; ++it) {
    int c    = it * 512 + tid;       // chunk id (16B each)
    int row  = c >> 4;               // 0..255
    int col8 = c & 15;               // 16B slot within row
    const u16* src = (c < 2048) ? &WsT[(long)c * 8] : &WnT[(long)(c - 2048) * 8];
    bf16x8 v = *(const bf16x8*)src;
    *(bf16x8*)&w_lds[row * D + (((col8) ^ (row & 15)) << 3)] = v;
  }
  __syncthreads();

  // ---- MFMA loop, weights from LDS (swizzled read) ----
  f32x4 acc[8] = {};
#pragma unroll
  for (int f = 0; f < 8; ++f) {
    const int wrow = f * 16 + l15;
#pragma unroll
    for (int ks = 0; ks < 4; ++ks) {
      const int cs = ((ks * 4 + g) ^ l15) << 3;   // row&15 == l15
      bf16x8 bS = *(const bf16x8*)&w_lds[wrow * D + cs];
      bf16x8 bA = *(const bf16x8*)&w_lds[D * D + wrow * D + cs];
      acc[f] = __builtin_amdgcn_mfma_f32_16x16x32_bf16(aS[ks], bS, acc[f], 0, 0, 0);
      acc[f] = __builtin_amdgcn_mfma_f32_16x16x32_bf16(aA[ks], bA, acc[f], 0, 0, 0);
    }
  }

  // ---- epilogue params (col = f*16 + l15) ----
  float bs[8], lgv[8], lbv[8];
#pragma unroll
  for (int f = 0; f < 8; ++f) {
    bs[f]  = bias[f * 16 + l15];
    lgv[f] = lg[f * 16 + l15];
    lbv[f] = lb[f * 16 + l15];
  }
#pragma unroll
  for (int f = 0; f < 8; ++f)
#pragma unroll
    for (int r = 0; r < 4; ++r) acc[f][r] += bs[f];

  long rowb[4];
  bool valid[4];
#pragma unroll
  for (int r = 0; r < 4; ++r) {
    rowb[r]  = base + w * 16 + g * 4 + r;
    valid[r] = rowb[r] < n;
  }

  // ---- graph segment sum over this wave's 16 rows (batch sorted) ----
  const int wb = w * 16;
  int b_first = batch_lds[wb], b_last = batch_lds[wb + 15];
  if (b_first == b_last) {
#pragma unroll
    for (int f = 0; f < 8; ++f) {
      float ps = 0.f;
#pragma unroll
      for (int r = 0; r < 4; ++r) if (valid[r]) ps += acc[f][r];
      ps += __shfl_xor(ps, 16);
      ps += __shfl_xor(ps, 32);
      if (lane < 16) atomicAdd(&gacc[b_first * D + f * 16 + lane], ps);
    }
  } else {
    int i = 0;
    while (i < 16) {                    // wave-uniform (LDS scalars)
      int bseg = batch_lds[wb + i];
      int j = i + 1;
      while (j < 16 && batch_lds[wb + j] == bseg) ++j;
#pragma unroll
      for (int f = 0; f < 8; ++f) {
        float ps = 0.f;
#pragma unroll
        for (int r = 0; r < 4; ++r) {
          int lr = g * 4 + r;
          if (valid[r] && lr >= i && lr < j) ps += acc[f][r];
        }
        ps += __shfl_xor(ps, 16);
        ps += __shfl_xor(ps, 32);
        if (lane < 16) atomicAdd(&gacc[bseg * D + f * 16 + lane], ps);
      }
      i = j;
    }
  }

  // ---- residual + LN + relu ----
  float xv[8][4];
  float s[4] = {0, 0, 0, 0}, q[4] = {0, 0, 0, 0};
#pragma unroll
  for (int r = 0; r < 4; ++r) {
    long row = valid[r] ? rowb[r] : (n - 1);
#pragma unroll
    for (int f = 0; f < 8; ++f) {
      float nv = bf2f(nodeB[row * D + f * 16 + l15]);
      float x  = acc[f][r] + nv;
      xv[f][r] = x;
      s[r] += x; q[r] += x * x;
    }
  }
#pragma unroll
  for (int r = 0; r < 4; ++r) {
#pragma unroll
    for (int m = 1; m < 16; m <<= 1) {
      s[r] += __shfl_xor(s[r], m);
      q[r] += __shfl_xor(q[r], m);
    }
  }
#pragma unroll
  for (int r = 0; r < 4; ++r) {
    if (!valid[r]) continue;
    float mean = s[r] * (1.f / 128.f);
    float var  = q[r] * (1.f / 128.f) - mean * mean;
    float rs   = rsqrtf(fmaxf(var, 0.f) + 1e-5f);
#pragma unroll
    for (int f = 0; f < 8; ++f) {
      float y = fmaxf((xv[f][r] - mean) * rs * lgv[f] + lbv[f], 0.f);
      if (nodeOutB) nodeOutB[rowb[r] * D + f * 16 + l15] = f2bf(y);
      if (nodeOutF) nodeOutF[rowb[r] * D + f * 16 + l15] = y;
    }
  }
}

// ================= graph LN: graph = LN(LN(gacc + graph)) =================
__global__ void k_ln_graph(const float* __restrict__ gacc,
                           float* __restrict__ graph,
                           const float* __restrict__ lg,
                           const float* __restrict__ lb)
{
  int row  = blockIdx.x;
  int lane = threadIdx.x;
  float2 gv = *(const float2*)&lg[lane * 2];
  float2 bv = *(const float2*)&lb[lane * 2];
  float2 a = *(const float2*)&gacc[row * D + lane * 2];
  float2 p = *(const float2*)&graph[row * D + lane * 2];
  float x0 = a.x + p.x, x1 = a.y + p.y;
#pragma unroll
  for (int pass = 0; pass < 2; ++pass) {
    float s = x0 + x1, q = x0 * x0 + x1 * x1;
#pragma unroll
    for (int m = 1; m < 64; m <<= 1) { s += __shfl_xor(s, m); q += __shfl_xor(q, m); }
    float mean = s * (1.f / 128.f);
    float var  = q * (1.f / 128.f) - mean * mean;
    float rs   = rsqrtf(fmaxf(var, 0.f) + 1e-5f);
    x0 = (x0 - mean) * rs * gv.x + bv.x;
    x1 = (x1 - mean) * rs * gv.y + bv.y;
  }
  float2 o; o.x = x0; o.y = x1;
  *(float2*)&graph[row * D + lane * 2] = o;
}

extern "C" void kernel_launch(void* const* d_in, const int* in_sizes, int n_in,
                              void* d_out, int out_size, void* d_ws, size_t ws_size,
                              hipStream_t stream)
{
  const float* x       = (const float*)d_in[0];
  const int*   edge    = (const int*)d_in[1];
  const int*   batch   = (const int*)d_in[2];
  const float* fc_w    = (const float*)d_in[3];
  const float* fc_b    = (const float*)d_in[4];
  const float* w_self  = (const float*)d_in[5];
  const float* w_neigh = (const float*)d_in[6];
  const float* conv_b  = (const float*)d_in[7];
  const float* ln_g    = (const float*)d_in[8];
  const float* ln_b    = (const float*)d_in[9];

  const int N = in_sizes[0] / D;
  const int E = in_sizes[1] / 2;
  const int* src = edge;
  const int* dst = edge + E;

  // ---- workspace layout ----
  int*   cnt      = (int*)d_ws;                 // N
  int*   rowptr   = cnt + N;                    // N
  int*   cursor   = rowptr + N;                 // N (ends as row-end)
  int*   bsum     = cursor + N;                 // 1024
  int*   csr_src  = bsum + 1024;                // E
  float* invdeg   = (float*)(csr_src + E);      // N
  float* gacc     = invdeg + N;                 // G*D
  float* graphbuf = gacc + NG * D;              // G*D
  // 16B-align the bf16 region
  char*  bfbase   = (char*)(graphbuf + NG * D);
  bfbase = (char*)(((size_t)bfbase + 15) & ~(size_t)15);
  u16*   nodeB    = (u16*)bfbase;               // N*D bf16
  u16*   aggB     = nodeB + (long)N * D;        // N*D bf16
  u16*   wsT      = aggB + (long)N * D;         // 3*128*128 bf16
  u16*   wnT      = wsT + 3 * D * D;            // 3*128*128 bf16
  u16*   fcT      = wnT + 3 * D * D;            // 128*128 bf16

  const int nb = (N + 1023) / 1024;
  const int psize = (N + NPART - 1) / NPART;

  hipMemsetAsync(cnt, 0, (size_t)N * sizeof(int), stream);
  hipMemsetAsync(graphbuf, 0, (size_t)NG * D * sizeof(float), stream);

  // ---- CSR build (once, XCD-partitioned) ----
  k_count<<<2048, 256, 0, stream>>>(dst, cnt, E, psize);
  k_invdeg<<<(N + 255) / 256, 256, 0, stream>>>(cnt, invdeg, N);
  k_blocksum<<<nb, 256, 0, stream>>>(cnt, bsum, N);
  k_scan_bsum<<<1, 1024, 0, stream>>>(bsum, nb);
  k_rowptr<<<nb, 256, 0, stream>>>(cnt, bsum, rowptr, cursor, N);
  k_fill<<<2048, 256, 0, stream>>>(src, dst, cursor, csr_src, E, psize);

  // ---- weight prep (bf16, transposed to [n][k]) ----
  k_wprep<<<192, 256, 0, stream>>>(w_self,  wsT, NL);
  k_wprep<<<192, 256, 0, stream>>>(w_neigh, wnT, NL);
  k_wprep<<<64, 256, 0, stream>>>(fc_w, fcT, 1);

  // ---- input projection: nodeB = bf16(x @ fc_w + fc_b), MFMA ----
  const int pblocks = (N + 63) / 64;
  k_proj_mfma<<<pblocks, 256, 0, stream>>>(x, fcT, fc_b, nodeB, N);

  const int cblocks = (N + 127) / 128;
  const int ablocks = (N + 15) / 16;
  for (int l = 0; l < NL; ++l) {
    hipMemsetAsync(gacc, 0, (size_t)NG * D * sizeof(float), stream);
    k_aggr<<<ablocks, 256, 0, stream>>>(nodeB, rowptr, cursor, invdeg,
                                        csr_src, aggB, N);
    const bool last = (l == NL - 1);
    k_conv_mfma<<<cblocks, 512, 0, stream>>>(
        nodeB, aggB, wsT + (long)l * D * D, wnT + (long)l * D * D,
        conv_b + l * D, ln_g + l * D, ln_b + l * D,
        batch, gacc,
        last ? nullptr : nodeB, last ? (float*)d_out : nullptr, N);
    k_ln_graph<<<NG, 64, 0, stream>>>(gacc, graphbuf, ln_g + l * D, ln_b + l * D);
  }

  // ---- graph output ----
  hipMemcpyAsync((float*)d_out + (long)N * D, graphbuf,
                 (size_t)NG * D * sizeof(float),
                 hipMemcpyDeviceToDevice, stream);
}